// Round 2
// 473.515 us; speedup vs baseline: 1.0236x; 1.0236x over previous
//
#include <hip/hip_runtime.h>

// GroupSparseActivation: x (32,2048,1024) fp32.
// v2 (resubmit — round-1 bench was an infra failure, no counters returned):
// split the barrier-coupled fused kernel into 3 streaming kernels so the
// memory phases run at full occupancy (fused grid was pinned at 512 blocks =
// 16 waves/CU = 50% cap; measured 2.3 TB/s, latency-bound).
//   K1 gsa_norms : 8192 blocks x 256 thr, 8 rows/block, batched loads ->
//                  exact-double 16-lane butterfly sumsq -> norms (4 MiB, (b,g,s))
//   K2 gsa_select: 512 blocks x 1 wave, 42-bit radix select on composite key
//                  (norm bits << 11) | (2047 - s)  [identical to v1 phase B]
//   K3 gsa_write : 8192 blocks x 256 thr, batched conditional loads (selected
//                  rows only, L3-hot) + 8 nontemporal stores
// Selection arithmetic is bit-identical to v1 (same summation tree, same
// fp32 norm rounding) => absmax must stay 0.
// Mandatory HBM: 256 R + 256 W + ~40 MiB aux => ~88 us floor at 6.3 TB/s.

#define BB 32
#define SS 2048
#define CC 1024
#define GG 16
#define KTOP 256
#define ROWS 8

typedef float f32x4 __attribute__((ext_vector_type(4)));

__device__ inline double shfl_xor_dbl(double v, int m) {
  union {
    double d;
    int i[2];
  } u;
  u.d = v;
  u.i[0] = __shfl_xor(u.i[0], m, 64);
  u.i[1] = __shfl_xor(u.i[1], m, 64);
  return u.d;
}

// ---------------- K1: group norms, full-occupancy stream ----------------
__global__ __launch_bounds__(256) void gsa_norms(const float4* __restrict__ x4,
                                                 float* __restrict__ nrm) {
  const int t = threadIdx.x;       // float4 index within a 1024-float row
  const int lane16 = t & 15;       // lane within the 64-ch group
  const int g = t >> 4;            // group 0..15
  const size_t base = (size_t)blockIdx.x * ROWS;  // global row = b*SS + s

  float4 vv[ROWS];
#pragma unroll
  for (int r = 0; r < ROWS; ++r) vv[r] = x4[(base + r) * 256 + t];

#pragma unroll
  for (int r = 0; r < ROWS; ++r) {
    const float4 v = vv[r];
    double d = (double)v.x * v.x + (double)v.y * v.y + (double)v.z * v.z +
               (double)v.w * v.w;
    d += shfl_xor_dbl(d, 1);
    d += shfl_xor_dbl(d, 2);
    d += shfl_xor_dbl(d, 4);
    d += shfl_xor_dbl(d, 8);
    if (lane16 == 0) {
      const size_t row = base + r;
      const int b = (int)(row >> 11);
      const int s = (int)(row & (SS - 1));
      nrm[((size_t)(b * GG + g) << 11) | s] = sqrtf(__fadd_rn((float)d, 1e-9f));
    }
  }
}

// ---------------- K2: per-(b,g) threshold via 42-bit radix select --------
__global__ __launch_bounds__(64) void gsa_select(
    const float* __restrict__ nrm, unsigned long long* __restrict__ Tarr) {
  const int row = blockIdx.x;  // b*GG + g
  const int t = threadIdx.x;   // 0..63
  unsigned long long key[SS / 64];
#pragma unroll
  for (int j = 0; j < SS / 64; ++j) {
    const int s = j * 64 + t;
    key[j] =
        ((unsigned long long)__float_as_uint(nrm[((size_t)row << 11) | s])
         << 11) |
        (unsigned)(SS - 1 - s);
  }
  unsigned long long T = 0ULL;
  for (int bit = 41; bit >= 0; --bit) {
    const unsigned long long cand = T | (1ULL << bit);
    int local = 0;
#pragma unroll
    for (int j = 0; j < SS / 64; ++j) local += (key[j] >= cand) ? 1 : 0;
    for (int m = 32; m >= 1; m >>= 1) local += __shfl_xor(local, m, 64);
    if (local >= KTOP) T = cand;
  }
  if (t == 0) Tarr[row] = T;
}

// ---------------- K3: masked passthrough, full-occupancy stream ----------
__global__ __launch_bounds__(256) void gsa_write(
    const float4* __restrict__ x4, const float* __restrict__ nrm,
    const unsigned long long* __restrict__ Tarr, float4* __restrict__ out4) {
  const int t = threadIdx.x;
  const int g = t >> 4;
  const size_t base = (size_t)blockIdx.x * ROWS;  // ROWS divides SS => one b
  const int b = (int)(base >> 11);
  const int s0 = (int)(base & (SS - 1));
  const unsigned long long T = Tarr[b * GG + g];

  float4 v[ROWS];
#pragma unroll
  for (int r = 0; r < ROWS; ++r) {
    const int s = s0 + r;
    const unsigned long long key =
        ((unsigned long long)__float_as_uint(
             nrm[((size_t)(b * GG + g) << 11) | s])
         << 11) |
        (unsigned)(SS - 1 - s);
    v[r] = make_float4(0.f, 0.f, 0.f, 0.f);
    if (key >= T) v[r] = x4[(base + r) * 256 + t];
  }
#pragma unroll
  for (int r = 0; r < ROWS; ++r) {
    __builtin_nontemporal_store(*(const f32x4*)&v[r],
                                (f32x4*)(out4 + (base + r) * 256 + t));
  }
}

// ---------------- v1 fused kernel (fallback if workspace too small) ------
__global__ __launch_bounds__(512) void gsa_fused(const float4* __restrict__ x4,
                                                 float4* __restrict__ out4) {
  __shared__ float norm[SS];
  __shared__ unsigned long long Tsh;
  const int t = threadIdx.x;
  const int lane16 = t & 15;
  const int srow = t >> 4;
  const int b = blockIdx.x >> 4;
  const int g = blockIdx.x & 15;
  const size_t bbase = (size_t)b * SS;
  const int chunk = g * 16 + lane16;

  for (int it = 0; it < SS / 32; ++it) {
    const int s = it * 32 + srow;
    float4 v = x4[(bbase + s) * 256 + chunk];
    double d = (double)v.x * v.x + (double)v.y * v.y + (double)v.z * v.z +
               (double)v.w * v.w;
    d += shfl_xor_dbl(d, 1);
    d += shfl_xor_dbl(d, 2);
    d += shfl_xor_dbl(d, 4);
    d += shfl_xor_dbl(d, 8);
    if (lane16 == 0) norm[s] = sqrtf(__fadd_rn((float)d, 1e-9f));
  }
  __syncthreads();

  if (t < 64) {
    unsigned long long key[32];
#pragma unroll
    for (int j = 0; j < 32; ++j) {
      const int s = j * 64 + t;
      key[j] = ((unsigned long long)__float_as_uint(norm[s]) << 11) |
               (unsigned)(SS - 1 - s);
    }
    unsigned long long T = 0ULL;
    for (int bit = 41; bit >= 0; --bit) {
      unsigned long long cand = T | (1ULL << bit);
      int local = 0;
#pragma unroll
      for (int j = 0; j < 32; ++j) local += (key[j] >= cand) ? 1 : 0;
      for (int m = 32; m >= 1; m >>= 1) local += __shfl_xor(local, m, 64);
      if (local >= KTOP) T = cand;
    }
    if (t == 0) Tsh = T;
  }
  __syncthreads();
  const unsigned long long T = Tsh;

  for (int it = 0; it < SS / 32; ++it) {
    const int s = it * 32 + srow;
    const unsigned long long key =
        ((unsigned long long)__float_as_uint(norm[s]) << 11) |
        (unsigned)(SS - 1 - s);
    float4 v = make_float4(0.f, 0.f, 0.f, 0.f);
    if (key >= T) v = x4[(bbase + s) * 256 + chunk];
    out4[(bbase + s) * 256 + chunk] = v;
  }
}

extern "C" void kernel_launch(void* const* d_in, const int* in_sizes, int n_in,
                              void* d_out, int out_size, void* d_ws,
                              size_t ws_size, hipStream_t stream) {
  const float4* x4 = (const float4*)d_in[0];
  float4* out4 = (float4*)d_out;
  const size_t nrm_bytes = (size_t)BB * GG * SS * sizeof(float);  // 4 MiB
  const size_t need = nrm_bytes + (size_t)BB * GG * sizeof(unsigned long long);
  if (d_ws != nullptr && ws_size >= need) {
    float* nrm = (float*)d_ws;
    unsigned long long* Tarr =
        (unsigned long long*)((char*)d_ws + nrm_bytes);
    gsa_norms<<<BB * SS / ROWS, 256, 0, stream>>>(x4, nrm);
    gsa_select<<<BB * GG, 64, 0, stream>>>(nrm, Tarr);
    gsa_write<<<BB * SS / ROWS, 256, 0, stream>>>(x4, nrm, Tarr, out4);
  } else {
    gsa_fused<<<BB * GG, 512, 0, stream>>>(x4, out4);
  }
}

// Round 3
// 473.473 us; speedup vs baseline: 1.0237x; 1.0001x over previous
//
#include <hip/hip_runtime.h>

// GroupSparseActivation: x (32,2048,1024) fp32.
// v3: back to the fused one-kernel-per-(b,g) topology (best L3 behavior:
// round-0 FETCH was 147 MiB < 256 MiB compulsory because x == L3 size and
// selected re-reads are temporally local), but at FULL occupancy:
//   512 blocks x 1024 threads, __launch_bounds__(1024,8) => 2 blocks/CU
//   = 32 waves/CU (v1 was 512 thr => 16 waves/CU, 41% occ, 2.3 TB/s,
//   latency-bound: ~16 KiB/CU in flight vs ~23 KiB needed at ~900 cyc).
// Phase A: 16 iters x 2 rows batched (2 KiB/wave in flight), exact-double
//          16-lane xor-butterfly sumsq -> norm[] in LDS (bit-identical to v1).
// Phase B: wave 0 only; 42-bit bisection kept bit-exact but compares are
//          lexicographic on (norm_bits, s) with counts from ballot+popc so
//          per-thread state is 32 x u32 (not 32 x u64) => fits 64 VGPR.
// Phase C: 16 iters x 2 rows; unselected rows skip the load; NT stores so
//          the 256 MiB output stream does not evict x from L3.
// Traffic: ~147 MiB read (L3-assisted) + 256 MiB write => ~65-80 us floor.

#define BB 32
#define SS 2048
#define GG 16
#define KTOP 256

typedef float f32x4 __attribute__((ext_vector_type(4)));

__device__ inline double shfl_xor_dbl(double v, int m) {
  union {
    double d;
    int i[2];
  } u;
  u.d = v;
  u.i[0] = __shfl_xor(u.i[0], m, 64);
  u.i[1] = __shfl_xor(u.i[1], m, 64);
  return u.d;
}

__global__ __launch_bounds__(1024, 8) void gsa_fused3(
    const float4* __restrict__ x4, float4* __restrict__ out4) {
  __shared__ float norm[SS];            // 8 KiB
  __shared__ unsigned int Tch_sh;       // threshold: norm-bits part
  __shared__ int Tscl_sh;               // threshold: max selected s at ==ch
  const int t = threadIdx.x;
  const int lane16 = t & 15;   // float4 chunk within the 64-ch group
  const int srow = t >> 4;     // 0..63: s-offset within an iteration
  const int b = blockIdx.x >> 4;
  const int g = blockIdx.x & 15;
  const size_t bbase = (size_t)b * SS;  // (b*SS + s) row index
  const int chunk = g * 16 + lane16;    // float4 index within a 256-float4 row

  // ---- Phase A: norms. 16 iters x 2 rows; butterfly tree identical to v1.
  for (int it = 0; it < 16; ++it) {
    const int s0 = it * 128 + srow;
    const int s1 = s0 + 64;
    const float4 va = x4[(bbase + s0) * 256 + chunk];
    const float4 vb = x4[(bbase + s1) * 256 + chunk];
    double da = (double)va.x * va.x + (double)va.y * va.y +
                (double)va.z * va.z + (double)va.w * va.w;
    double db = (double)vb.x * vb.x + (double)vb.y * vb.y +
                (double)vb.z * vb.z + (double)vb.w * vb.w;
    da += shfl_xor_dbl(da, 1);
    db += shfl_xor_dbl(db, 1);
    da += shfl_xor_dbl(da, 2);
    db += shfl_xor_dbl(db, 2);
    da += shfl_xor_dbl(da, 4);
    db += shfl_xor_dbl(db, 4);
    da += shfl_xor_dbl(da, 8);
    db += shfl_xor_dbl(db, 8);
    if (lane16 == 0) {
      norm[s0] = sqrtf(__fadd_rn((float)da, 1e-9f));
      norm[s1] = sqrtf(__fadd_rn((float)db, 1e-9f));
    }
  }
  __syncthreads();

  // ---- Phase B: wave 0: bisection for T = K-th largest composite key
  // key = (norm_bits << 11) | (2047 - s); all keys distinct.
  // Lexicographic compare keeps per-thread state at 32 x u32.
  if (t < 64) {
    unsigned int nb[32];
#pragma unroll
    for (int j = 0; j < 32; ++j) nb[j] = __float_as_uint(norm[j * 64 + t]);
    unsigned long long T = 0ULL;
    for (int bit = 41; bit >= 0; --bit) {
      const unsigned long long cand = T | (1ULL << bit);
      const unsigned int ch = (unsigned int)(cand >> 11);
      const int scl = 2047 - (int)(cand & 2047ULL);  // key>=cand <=> s<=scl @ ==ch
      int cnt = 0;
#pragma unroll
      for (int j = 0; j < 32; ++j) {
        const bool pred =
            (nb[j] > ch) | ((nb[j] == ch) & ((t + j * 64) <= scl));
        cnt += (int)__popcll(__ballot(pred));
      }
      if (cnt >= KTOP) T = cand;
    }
    if (t == 0) {
      Tch_sh = (unsigned int)(T >> 11);
      Tscl_sh = 2047 - (int)(T & 2047ULL);
    }
  }
  __syncthreads();
  const unsigned int ch = Tch_sh;
  const int scl = Tscl_sh;

  // ---- Phase C: masked passthrough; unselected rows skip the load.
  for (int it = 0; it < 16; ++it) {
    const int s0 = it * 128 + srow;
    const int s1 = s0 + 64;
    const unsigned int n0 = __float_as_uint(norm[s0]);
    const unsigned int n1 = __float_as_uint(norm[s1]);
    const bool sel0 = (n0 > ch) | ((n0 == ch) & (s0 <= scl));
    const bool sel1 = (n1 > ch) | ((n1 == ch) & (s1 <= scl));
    float4 v0 = make_float4(0.f, 0.f, 0.f, 0.f);
    float4 v1 = make_float4(0.f, 0.f, 0.f, 0.f);
    if (sel0) v0 = x4[(bbase + s0) * 256 + chunk];
    if (sel1) v1 = x4[(bbase + s1) * 256 + chunk];
    __builtin_nontemporal_store(*(const f32x4*)&v0,
                                (f32x4*)(out4 + (bbase + s0) * 256 + chunk));
    __builtin_nontemporal_store(*(const f32x4*)&v1,
                                (f32x4*)(out4 + (bbase + s1) * 256 + chunk));
  }
}

extern "C" void kernel_launch(void* const* d_in, const int* in_sizes, int n_in,
                              void* d_out, int out_size, void* d_ws,
                              size_t ws_size, hipStream_t stream) {
  const float4* x4 = (const float4*)d_in[0];
  float4* out4 = (float4*)d_out;
  gsa_fused3<<<BB * GG, 1024, 0, stream>>>(x4, out4);
}